// Round 4
// baseline (135.110 us; speedup 1.0000x reference)
//
#include <hip/hip_runtime.h>
#include <math.h>

#define GREEDY_EPS 1e-6f
#define SEG 8          // segments per row
#define BLK 512        // threads per block (8 waves)

typedef float f32x4 __attribute__((ext_vector_type(4)));

// Monotone float->uint key: a > b  <=>  fkey(a) > fkey(b)  (no NaNs in data)
__device__ inline unsigned int fkey(float v) {
    unsigned int b = __float_as_uint(v);
    return (b & 0x80000000u) ? ~b : (b | 0x80000000u);
}

// Single-pass sampler with in-kernel cross-block finisher.
// ws layout: [0, B*8)  u64 per-row running max (packed key|~idx), zeroed per call
//            [B*8, B*12) u32 per-row arrival counters, zeroed per call
// All packed keys are > 0 (fkey(-inf) = 0x007FFFFF), so 0 is the identity.
__global__ __launch_bounds__(BLK) void sampler_fused(
    const float* __restrict__ logits,
    const float* __restrict__ temps,
    const float* __restrict__ u,
    unsigned long long* __restrict__ wsMax,
    unsigned int* __restrict__ wsCnt,
    int* __restrict__ out,
    int V)
{
    const int row = blockIdx.x >> 3;      // SEG == 8
    const int seg = blockIdx.x & 7;
    const int tid = threadIdx.x;

    const int segLen = V / SEG;           // 16000, divisible by 4
    const int segOff = seg * segLen;
    const int nvec   = segLen >> 2;       // 4000 float4s

    const float t = temps[row];
    const bool greedy = (t <= GREEDY_EPS);

    const f32x4* __restrict__ lg4 =
        (const f32x4*)(logits + (size_t)row * (size_t)V + segOff);
    const f32x4* __restrict__ uu4 =
        (const f32x4*)(u + (size_t)row * (size_t)V + segOff);

    float bestVal = -INFINITY;
    int bestIdx = 0;

    if (greedy) {
        #pragma unroll 4
        for (int i = tid; i < nvec; i += BLK) {
            f32x4 l = lg4[i];
            int base = i << 2;
            if (l.x > bestVal) { bestVal = l.x; bestIdx = base; }
            if (l.y > bestVal) { bestVal = l.y; bestIdx = base + 1; }
            if (l.z > bestVal) { bestVal = l.z; bestIdx = base + 2; }
            if (l.w > bestVal) { bestVal = l.w; bestIdx = base + 3; }
        }
    } else {
        // argmax(l/t + g) == argmax(l + t*g), t > 0.
        // g = -log(-log u) = -ln2*(log2(-log2 u) + log2(ln2))
        const float a   = -t * 0.69314718055994530942f;
        const float ac1 = a * -0.52876637294489770425f;
        #pragma unroll 4
        for (int i = tid; i < nvec; i += BLK) {
            f32x4 l = lg4[i];
            f32x4 g = __builtin_nontemporal_load(&uu4[i]);
            int base = i << 2;
            float G0 = __log2f(-__log2f(g.x));
            float G1 = __log2f(-__log2f(g.y));
            float G2 = __log2f(-__log2f(g.z));
            float G3 = __log2f(-__log2f(g.w));
            float v0 = fmaf(a, G0, l.x + ac1);
            float v1 = fmaf(a, G1, l.y + ac1);
            float v2 = fmaf(a, G2, l.z + ac1);
            float v3 = fmaf(a, G3, l.w + ac1);
            if (v0 > bestVal) { bestVal = v0; bestIdx = base; }
            if (v1 > bestVal) { bestVal = v1; bestIdx = base + 1; }
            if (v2 > bestVal) { bestVal = v2; bestIdx = base + 2; }
            if (v3 > bestVal) { bestVal = v3; bestIdx = base + 3; }
        }
    }

    // Wave reduction, tie-break prefers lower index.
    const int lane = tid & 63;
    const int wave = tid >> 6;
    #pragma unroll
    for (int off = 32; off > 0; off >>= 1) {
        float ov = __shfl_down(bestVal, off);
        int   oi = __shfl_down(bestIdx, off);
        if (ov > bestVal || (ov == bestVal && oi < bestIdx)) {
            bestVal = ov; bestIdx = oi;
        }
    }

    __shared__ float sVal[BLK / 64];
    __shared__ int   sIdx[BLK / 64];
    if (lane == 0) { sVal[wave] = bestVal; sIdx[wave] = bestIdx; }
    __syncthreads();

    if (tid == 0) {
        float bv = sVal[0]; int bi = sIdx[0];
        #pragma unroll
        for (int w = 1; w < BLK / 64; ++w) {
            float v = sVal[w]; int ix = sIdx[w];
            if (v > bv || (v == bv && ix < bi)) { bv = v; bi = ix; }
        }
        int gidx = bi + segOff;
        unsigned long long packed =
            ((unsigned long long)fkey(bv) << 32) |
            (unsigned long long)(0xFFFFFFFFu - (unsigned int)gidx);

        // Publish partial, then signal arrival (device-scope atomics).
        atomicMax(&wsMax[row], packed);
        __threadfence();
        unsigned int prev = atomicAdd(&wsCnt[row], 1u);
        if (prev == SEG - 1) {
            // Last block for this row: atomically read the final max
            // (atomicMax with 0 returns current value, coherent device-wide).
            unsigned long long m = atomicMax(&wsMax[row], 0ULL);
            out[row] = (int)(0xFFFFFFFFu - (unsigned int)(m & 0xFFFFFFFFu));
        }
    }
}

extern "C" void kernel_launch(void* const* d_in, const int* in_sizes, int n_in,
                              void* d_out, int out_size, void* d_ws, size_t ws_size,
                              hipStream_t stream) {
    const float* logits = (const float*)d_in[0];
    const float* temps  = (const float*)d_in[1];
    const float* u      = (const float*)d_in[2];
    int* out = (int*)d_out;

    const int B = in_sizes[1];            // 256
    const int V = in_sizes[0] / B;        // 128000

    unsigned long long* wsMax = (unsigned long long*)d_ws;
    unsigned int* wsCnt = (unsigned int*)((char*)d_ws + (size_t)B * 8);

    // Zero the per-row max + counter area (B*12 bytes) every call.
    hipMemsetAsync(d_ws, 0, (size_t)B * 12, stream);

    sampler_fused<<<dim3(B * SEG), dim3(BLK), 0, stream>>>(
        logits, temps, u, wsMax, wsCnt, out, V);
}

// Round 5
// 46.105 us; speedup vs baseline: 2.9305x; 2.9305x over previous
//
#include <hip/hip_runtime.h>
#include <math.h>

#define GREEDY_EPS 1e-6f
#define SEG 4          // segments per row
#define BLK 1024       // threads per block (16 waves)

typedef float f32x4 __attribute__((ext_vector_type(4)));

// Monotone float->uint key: a > b  <=>  fkey(a) > fkey(b)  (no NaNs in data)
__device__ inline unsigned int fkey(float v) {
    unsigned int b = __float_as_uint(v);
    return (b & 0x80000000u) ? ~b : (b | 0x80000000u);
}

// Phase 1: each block computes argmax over one contiguous segment of a row.
// Each thread handles a contiguous PAIR of float4s per iteration (32 B) ->
// 4 independent 16 B loads in flight per thread (2x the MLP of R3).
// NO device-scope fences/atomics here (R4 lesson: they wreck L2 streaming).
__global__ __launch_bounds__(BLK) void sampler_partial(
    const float* __restrict__ logits,
    const float* __restrict__ temps,
    const float* __restrict__ u,
    unsigned long long* __restrict__ ws,
    int V)
{
    const int row = blockIdx.x >> 2;      // SEG == 4
    const int seg = blockIdx.x & 3;
    const int tid = threadIdx.x;

    const int segLen = V / SEG;           // 32000, divisible by 8
    const int segOff = seg * segLen;
    const int npair  = segLen >> 3;       // 4000 float4-pairs

    const float t = temps[row];
    const bool greedy = (t <= GREEDY_EPS);

    const f32x4* __restrict__ lg4 =
        (const f32x4*)(logits + (size_t)row * (size_t)V + segOff);
    const f32x4* __restrict__ uu4 =
        (const f32x4*)(u + (size_t)row * (size_t)V + segOff);

    float bestVal = -INFINITY;
    int bestIdx = 0;

    if (greedy) {
        for (int p = tid; p < npair; p += BLK) {
            f32x4 la = lg4[2 * p];
            f32x4 lb = lg4[2 * p + 1];
            int base = p << 3;
            if (la.x > bestVal) { bestVal = la.x; bestIdx = base; }
            if (la.y > bestVal) { bestVal = la.y; bestIdx = base + 1; }
            if (la.z > bestVal) { bestVal = la.z; bestIdx = base + 2; }
            if (la.w > bestVal) { bestVal = la.w; bestIdx = base + 3; }
            if (lb.x > bestVal) { bestVal = lb.x; bestIdx = base + 4; }
            if (lb.y > bestVal) { bestVal = lb.y; bestIdx = base + 5; }
            if (lb.z > bestVal) { bestVal = lb.z; bestIdx = base + 6; }
            if (lb.w > bestVal) { bestVal = lb.w; bestIdx = base + 7; }
        }
    } else {
        // argmax(l/t + g) == argmax(l + t*g), t > 0.
        // g = -log(-log u) = -ln2*(log2(-log2 u) + log2(ln2))
        // value = fma(a, log2(-log2 u), l + a*log2(ln2)), a = -t*ln2
        const float a   = -t * 0.69314718055994530942f;
        const float ac1 = a * -0.52876637294489770425f;
        for (int p = tid; p < npair; p += BLK) {
            f32x4 la = lg4[2 * p];
            f32x4 lb = lg4[2 * p + 1];
            f32x4 ga = __builtin_nontemporal_load(&uu4[2 * p]);
            f32x4 gb = __builtin_nontemporal_load(&uu4[2 * p + 1]);
            int base = p << 3;
            float v0 = fmaf(a, __log2f(-__log2f(ga.x)), la.x + ac1);
            float v1 = fmaf(a, __log2f(-__log2f(ga.y)), la.y + ac1);
            float v2 = fmaf(a, __log2f(-__log2f(ga.z)), la.z + ac1);
            float v3 = fmaf(a, __log2f(-__log2f(ga.w)), la.w + ac1);
            float v4 = fmaf(a, __log2f(-__log2f(gb.x)), lb.x + ac1);
            float v5 = fmaf(a, __log2f(-__log2f(gb.y)), lb.y + ac1);
            float v6 = fmaf(a, __log2f(-__log2f(gb.z)), lb.z + ac1);
            float v7 = fmaf(a, __log2f(-__log2f(gb.w)), lb.w + ac1);
            if (v0 > bestVal) { bestVal = v0; bestIdx = base; }
            if (v1 > bestVal) { bestVal = v1; bestIdx = base + 1; }
            if (v2 > bestVal) { bestVal = v2; bestIdx = base + 2; }
            if (v3 > bestVal) { bestVal = v3; bestIdx = base + 3; }
            if (v4 > bestVal) { bestVal = v4; bestIdx = base + 4; }
            if (v5 > bestVal) { bestVal = v5; bestIdx = base + 5; }
            if (v6 > bestVal) { bestVal = v6; bestIdx = base + 6; }
            if (v7 > bestVal) { bestVal = v7; bestIdx = base + 7; }
        }
    }

    // Wave reduction, tie-break prefers lower index.
    const int lane = tid & 63;
    const int wave = tid >> 6;
    #pragma unroll
    for (int off = 32; off > 0; off >>= 1) {
        float ov = __shfl_down(bestVal, off);
        int   oi = __shfl_down(bestIdx, off);
        if (ov > bestVal || (ov == bestVal && oi < bestIdx)) {
            bestVal = ov; bestIdx = oi;
        }
    }

    __shared__ float sVal[BLK / 64];
    __shared__ int   sIdx[BLK / 64];
    if (lane == 0) { sVal[wave] = bestVal; sIdx[wave] = bestIdx; }
    __syncthreads();

    if (tid == 0) {
        float bv = sVal[0]; int bi = sIdx[0];
        #pragma unroll
        for (int w = 1; w < BLK / 64; ++w) {
            float v = sVal[w]; int ix = sIdx[w];
            if (v > bv || (v == bv && ix < bi)) { bv = v; bi = ix; }
        }
        int gidx = bi + segOff;
        unsigned long long packed =
            ((unsigned long long)fkey(bv) << 32) |
            (unsigned long long)(0xFFFFFFFFu - (unsigned int)gidx);
        ws[(size_t)row * SEG + seg] = packed;
    }
}

// Phase 2: reduce SEG partials per row, decode index.
__global__ void sampler_final(const unsigned long long* __restrict__ ws,
                              int* __restrict__ out, int B)
{
    int row = blockIdx.x * blockDim.x + threadIdx.x;
    if (row < B) {
        unsigned long long m = ws[(size_t)row * SEG];
        #pragma unroll
        for (int s = 1; s < SEG; ++s) {
            unsigned long long v = ws[(size_t)row * SEG + s];
            if (v > m) m = v;
        }
        out[row] = (int)(0xFFFFFFFFu - (unsigned int)(m & 0xFFFFFFFFu));
    }
}

extern "C" void kernel_launch(void* const* d_in, const int* in_sizes, int n_in,
                              void* d_out, int out_size, void* d_ws, size_t ws_size,
                              hipStream_t stream) {
    const float* logits = (const float*)d_in[0];
    const float* temps  = (const float*)d_in[1];
    const float* u      = (const float*)d_in[2];
    int* out = (int*)d_out;

    const int B = in_sizes[1];            // 256
    const int V = in_sizes[0] / B;        // 128000

    unsigned long long* ws = (unsigned long long*)d_ws;

    sampler_partial<<<dim3(B * SEG), dim3(BLK), 0, stream>>>(
        logits, temps, u, ws, V);
    sampler_final<<<dim3((B + 255) / 256), dim3(256), 0, stream>>>(ws, out, B);
}